// Round 4
// baseline (156.455 us; speedup 1.0000x reference)
//
#include <hip/hip_runtime.h>

// Mean aggregator: out[n,:] = (1/K) * sum_k weight[idx[n,k],:]
// N = 100000 nodes, K = 10 neighbors, D = 128 feat (fp32).
//
// 32 lanes per node, one float4 (16B) per lane = 512B/row per half-wave,
// fully coalesced global_load_dwordx4 gathers.
//
// R4 change: force ALL 10 gathers in flight simultaneously. R3 showed
// VGPR_Count=24 -> compiler recycled load destinations, sustaining only
// ~4 outstanding loads/thread; the random gather is latency*concurrency
// bound (3.0 TB/s beyond-L2 at ~300ns miss latency ~ 27 lines/CU in
// flight). Load phase -> sched_barrier(0) -> add phase keeps 10 float4
// destinations live (~56-60 VGPR, still 8 waves/SIMD).

#define AGG_K 10
#define AGG_D 128

__global__ __launch_bounds__(256, 8) void Aggregator_26439818674919_kernel(
    const float* __restrict__ weight,
    const int* __restrict__ nidx,
    float* __restrict__ out,
    int n_nodes) {
  const int tid  = blockIdx.x * 256 + threadIdx.x;
  const int node = tid >> 5;   // 32 lanes per node
  const int lane = tid & 31;   // lane*4 floats within the row
  if (node >= n_nodes) return;

  const int ibase = node * AGG_K;
  int idx[AGG_K];
#pragma unroll
  for (int k = 0; k < AGG_K; ++k) {
    idx[k] = __builtin_nontemporal_load(&nidx[ibase + k]);
  }

  // Phase 1: issue all 10 row-gathers; keep every destination live.
  // 32-bit element offsets (max 100000*128 < 2^24) -> saddr-form loads.
  float4 v[AGG_K];
#pragma unroll
  for (int k = 0; k < AGG_K; ++k) {
    const unsigned off = (unsigned)idx[k] * AGG_D + (unsigned)(lane * 4);
    v[k] = *reinterpret_cast<const float4*>(&weight[off]);
  }

  // Pin: no accumulation may be scheduled before all loads are issued.
  __builtin_amdgcn_sched_barrier(0);

  // Phase 2: reduce.
  float4 acc = make_float4(0.f, 0.f, 0.f, 0.f);
#pragma unroll
  for (int k = 0; k < AGG_K; ++k) {
    acc.x += v[k].x; acc.y += v[k].y; acc.z += v[k].z; acc.w += v[k].w;
  }
  const float s = 1.0f / AGG_K;
  acc.x *= s; acc.y *= s; acc.z *= s; acc.w *= s;

  float* op = &out[(size_t)node * AGG_D + lane * 4];
  __builtin_nontemporal_store(acc.x, op + 0);
  __builtin_nontemporal_store(acc.y, op + 1);
  __builtin_nontemporal_store(acc.z, op + 2);
  __builtin_nontemporal_store(acc.w, op + 3);
}

extern "C" void kernel_launch(void* const* d_in, const int* in_sizes, int n_in,
                              void* d_out, int out_size, void* d_ws, size_t ws_size,
                              hipStream_t stream) {
  const float* weight = (const float*)d_in[0];
  const int*   nidx   = (const int*)d_in[1];
  float*       out    = (float*)d_out;

  const int n_nodes = in_sizes[1] / AGG_K;          // 100000
  const int total_threads = n_nodes * 32;           // 32 lanes per node
  const int blocks = (total_threads + 255) / 256;   // 12500

  Aggregator_26439818674919_kernel<<<blocks, 256, 0, stream>>>(
      weight, nidx, out, n_nodes);
}

// Round 5
// 154.922 us; speedup vs baseline: 1.0099x; 1.0099x over previous
//
#include <hip/hip_runtime.h>

// Mean aggregator: out[n,:] = (1/K) * sum_k weight[idx[n,k],:]
// N = 100000 nodes, K = 10 neighbors, D = 128 feat (fp32).
//
// 32 lanes per node, one float4 (16B) per lane = 512B/row per half-wave,
// fully coalesced global_load_dwordx4 gathers.
//
// R5 change: R4's all-loads-live attempt never reached codegen (VGPR
// stayed 24 -> compiler rebatched loads into small vmcnt groups, ~4 in
// flight/thread). Force 10 outstanding gathers via inline-asm
// global_load_dwordx4 with distinct "=v" destinations; asm-volatile
// ordering pins issue order, results stay live until the reduce. One
// s_waitcnt vmcnt(0) + sched_barrier(0) fence before consumption
// (guide rule #18: reg-only consumers can be hoisted past asm waitcnt).

#define AGG_K 10
#define AGG_D 128

typedef float f32x4 __attribute__((ext_vector_type(4)));

__global__ __launch_bounds__(256) void Aggregator_26439818674919_kernel(
    const float* __restrict__ weight,
    const int* __restrict__ nidx,
    float* __restrict__ out,
    int n_nodes) {
  const int tid  = blockIdx.x * 256 + threadIdx.x;
  const int node = tid >> 5;   // 32 lanes per node
  const int lane = tid & 31;   // lane*4 floats within the row
  if (node >= n_nodes) return;

  const int ibase = node * AGG_K;
  int idx[AGG_K];
#pragma unroll
  for (int k = 0; k < AGG_K; ++k) idx[k] = nidx[ibase + k];

  const unsigned lane_off = (unsigned)(lane * 4);

  // Issue all 10 row-gathers back-to-back; volatile asm preserves issue
  // order and forces distinct live destination registers (~40 VGPR data).
  f32x4 v0, v1, v2, v3, v4, v5, v6, v7, v8, v9;
#define AGG_LD(i, dst)                                                        \
  {                                                                           \
    const float* p = weight + (size_t)((unsigned)idx[i] * AGG_D + lane_off);  \
    asm volatile("global_load_dwordx4 %0, %1, off" : "=v"(dst) : "v"(p));     \
  }
  AGG_LD(0, v0) AGG_LD(1, v1) AGG_LD(2, v2) AGG_LD(3, v3) AGG_LD(4, v4)
  AGG_LD(5, v5) AGG_LD(6, v6) AGG_LD(7, v7) AGG_LD(8, v8) AGG_LD(9, v9)
#undef AGG_LD

  // Drain all 10, then hard-fence so the (register-only) adds below
  // cannot be scheduled above the waitcnt (rule #18).
  asm volatile("s_waitcnt vmcnt(0)" ::: "memory");
  __builtin_amdgcn_sched_barrier(0);

  f32x4 acc = v0 + v1;
  f32x4 acc2 = v2 + v3;
  f32x4 acc3 = v4 + v5;
  f32x4 acc4 = v6 + v7;
  acc += v8; acc2 += v9;
  acc += acc3; acc2 += acc4;
  acc += acc2;
  acc *= (1.0f / AGG_K);

  float* op = &out[(size_t)node * AGG_D + lane_off];
  *reinterpret_cast<f32x4*>(op) = acc;
}

extern "C" void kernel_launch(void* const* d_in, const int* in_sizes, int n_in,
                              void* d_out, int out_size, void* d_ws, size_t ws_size,
                              hipStream_t stream) {
  const float* weight = (const float*)d_in[0];
  const int*   nidx   = (const int*)d_in[1];
  float*       out    = (float*)d_out;

  const int n_nodes = in_sizes[1] / AGG_K;          // 100000
  const int total_threads = n_nodes * 32;           // 32 lanes per node
  const int blocks = (total_threads + 255) / 256;   // 12500

  Aggregator_26439818674919_kernel<<<blocks, 256, 0, stream>>>(
      weight, nidx, out, n_nodes);
}